// Round 1
// baseline (777.958 us; speedup 1.0000x reference)
//
#include <hip/hip_runtime.h>
#include <hip/hip_bf16.h>

// ---------------------------------------------------------------------------
// SLENet fused forward on MI355X.
//  kernel A: reduce over warp_ctfeat -> KV[8][12][12], Ksum[96] stats (MFMA)
//  finalize: BD/CM/Ksum derived tables
//  kernel B: per-64-token tile, 9 chained bf16-MFMA GEMMs + LNs, all in LDS
// Q=1+E decomposition keeps the tiny attention signal out of bf16 rounding.
// ---------------------------------------------------------------------------

typedef __attribute__((ext_vector_type(8))) short short8;
typedef __attribute__((ext_vector_type(4))) float f32x4;
typedef __attribute__((ext_vector_type(4))) unsigned int uint4v;

#define WS_FLAG 0
#define WS_PKV  512
#define WS_PSV  (WS_PKV + 16*9216*4)
#define WS_PSE  (WS_PSV + 16*96*4)
#define WS_KSUM (WS_PSE + 16*96*4)
#define WS_KSTOT (WS_KSUM + 96*4)
#define WS_CM   (WS_KSTOT + 64)
#define WS_BDT  (WS_CM + 768*4)
#define WS_WB   (WS_BDT + 9216*2)
#define WS_VEC  (WS_WB + 165888*2)

// weight offsets in bf16 elements inside WS_WB
#define OQKV   0
#define OQKV2  9216
#define OWQ    18432
#define OWK    27648
#define OWV    36864
#define OMERGE 46080
#define OW1    55296
#define OW2    92160
#define OFC1   110592
#define OFC2   147456
// vector offsets (f32) inside WS_VEC
#define VLN1W 0
#define VLN1B 96
#define VLN2W 192
#define VLN2B 384
#define VFC1B 576
#define VFC2B 768
#define VSA1W 864
#define VSA1B 960
#define VSA2W 1056
#define VSA2B 1152

struct InPtrs { const void* p[23]; };

__device__ inline float b2f(unsigned short x) {
  union { unsigned u; float f; } c; c.u = ((unsigned)x) << 16; return c.f;
}
__device__ inline unsigned short f2b(float f) {
  __hip_bfloat16 h = __float2bfloat16(f);
  return *(unsigned short*)&h;
}
__device__ inline uint2 pack4bf(float v0, float v1, float v2, float v3) {
  uint2 r;
  r.x = (unsigned)f2b(v0) | ((unsigned)f2b(v1) << 16);
  r.y = (unsigned)f2b(v2) | ((unsigned)f2b(v3) << 16);
  return r;
}

// ---------------- dtype probe: even-index u16s look like bf16 only if bf16 --
__global__ void probe_k(const void* in0, unsigned* flag) {
  int tid = threadIdx.x;
  const unsigned short* u = (const unsigned short*)in0;
  int cnt = 0;
  for (int j = 0; j < 8; ++j) {
    unsigned short v = u[(tid * 8 + j) * 2];
    unsigned e = (v >> 7) & 0xFF;
    if ((e >= 110 && e <= 141) || ((v & 0x7FFF) == 0)) cnt++;
  }
  for (int o = 32; o; o >>= 1) cnt += __shfl_down(cnt, o);
  if (tid == 0) *flag = (cnt > 256) ? 1u : 0u;
}

// ---------------- prep: weights->bf16, vectors->f32, zero reduction buffers -
template<int ISBF>
__launch_bounds__(256)
__global__ void prep_k(InPtrs ip, char* ws) {
  if (((const unsigned*)ws)[0] != (unsigned)ISBF) return;
  const int wsrc[10] = {3,4,13,14,15,16,17,18,9,11};
  const int wdst[11] = {0,9216,18432,27648,36864,46080,55296,92160,110592,147456,165888};
  const int vsrc[10] = {5,6,7,8,10,12,19,20,21,22};
  const int vdst[11] = {0,96,192,384,576,768,864,960,1056,1152,1248};
  unsigned short* wb = (unsigned short*)(ws + WS_WB);
  float* vec = (float*)(ws + WS_VEC);
  float* zr = (float*)(ws + WS_PKV);
  const int TOT = 165888 + 1248 + 150528;
  for (int e = blockIdx.x * 256 + threadIdx.x; e < TOT; e += gridDim.x * 256) {
    if (e < 165888) {
      int w = 0;
      while (w < 9 && e >= wdst[w + 1]) ++w;
      int loc = e - wdst[w];
      if (ISBF) wb[e] = ((const unsigned short*)ip.p[wsrc[w]])[loc];
      else      wb[e] = f2b(((const float*)ip.p[wsrc[w]])[loc]);
    } else if (e < 165888 + 1248) {
      int e2 = e - 165888;
      int w = 0;
      while (w < 9 && e2 >= vdst[w + 1]) ++w;
      int loc = e2 - vdst[w];
      vec[e2] = ISBF ? b2f(((const unsigned short*)ip.p[vsrc[w]])[loc])
                     : ((const float*)ip.p[vsrc[w]])[loc];
    } else {
      zr[e - 165888 - 1248] = 0.0f;
    }
  }
}

// ---------------- generic fragment GEMM helpers ----------------------------
template<int NB, int NCF, int KSTEPS>
__device__ inline void domm(const unsigned short* A, int apitch,
                            const unsigned short* B, int bpitch, int cf0,
                            int lane, f32x4 (&acc)[NB][NCF]) {
  int lr = lane & 15, lg = lane >> 4;
#pragma unroll
  for (int ks = 0; ks < KSTEPS; ++ks) {
    int k0 = ks * 32 + lg * 8;
    short8 bf[NCF];
#pragma unroll
    for (int cf = 0; cf < NCF; ++cf)
      bf[cf] = *(const short8*)(B + ((cf0 + cf) * 16 + lr) * bpitch + k0);
    short8 af[NB];
#pragma unroll
    for (int b = 0; b < NB; ++b)
      af[b] = *(const short8*)(A + (b * 16 + lr) * apitch + k0);
#pragma unroll
    for (int cf = 0; cf < NCF; ++cf)
#pragma unroll
      for (int b = 0; b < NB; ++b)
        acc[b][cf] = __builtin_amdgcn_mfma_f32_16x16x32_bf16(af[b], bf[cf], acc[b][cf], 0, 0, 0);
  }
}

template<int NB, int NCF>
__device__ inline void writeFrags(unsigned short* dst, int pitch, int cf0,
                                  int lane, f32x4 (&acc)[NB][NCF]) {
  int lr = lane & 15, lg = lane >> 4;
#pragma unroll
  for (int b = 0; b < NB; ++b)
#pragma unroll
    for (int cf = 0; cf < NCF; ++cf)
#pragma unroll
      for (int r = 0; r < 4; ++r) {
        float v = acc[b][cf][r];
        float v1 = __shfl_xor(v, 1);
        float v2 = __shfl_xor(v, 2);
        float v3 = __shfl_xor(v, 3);
        if ((lane & 3) == 0) {
          int row = b * 16 + lg * 4 + r;
          int col = (cf0 + cf) * 16 + lr;
          *(uint2*)(dst + row * pitch + col) = pack4bf(v, v1, v2, v3);
        }
      }
}

template<int NB, int NCF>
__device__ inline void zacc(f32x4 (&acc)[NB][NCF]) {
#pragma unroll
  for (int b = 0; b < NB; ++b)
#pragma unroll
    for (int cf = 0; cf < NCF; ++cf)
      acc[b][cf] = (f32x4){0.f, 0.f, 0.f, 0.f};
}

// ---------------- kernel A: stats over warp_ctfeat --------------------------
template<int ISBF>
__launch_bounds__(256)
__global__ void kA(const void* ct_, char* ws) {
  if (((const unsigned*)ws)[0] != (unsigned)ISBF) return;
  __shared__ unsigned short sCT[64][104];
  __shared__ unsigned short sEK[96][72];   // elu(k)^T : [hd][token]
  __shared__ unsigned short sVT[96][72];   // v^T      : [hv][token]
  const unsigned short* Wb = (const unsigned short*)(ws + WS_WB);
  float* pKV = (float*)(ws + WS_PKV);
  int tid = threadIdx.x, lane = tid & 63, wid = tid >> 6;
  int lr = lane & 15, lg = lane >> 4;

  f32x4 kvacc[2][6];
  zacc<2, 6>(kvacc);
  float accEk = 0.f, accV = 0.f;

  for (int t = blockIdx.x; t < 4096; t += gridDim.x) {
    // stage ct tile [64][96] -> sCT bf16
    if (ISBF) {
      const uint4v* src = (const uint4v*)((const unsigned short*)ct_ + (size_t)t * 6144);
#pragma unroll
      for (int i = 0; i < 3; ++i) {
        int ch = tid * 3 + i;
        int r = ch / 12, c = (ch % 12) * 8;
        *(uint4v*)&sCT[r][c] = src[ch];
      }
    } else {
      const float4* src = (const float4*)((const float*)ct_ + (size_t)t * 6144);
#pragma unroll
      for (int i = 0; i < 6; ++i) {
        int ch = tid * 6 + i;
        int r = ch / 24, c = (ch % 24) * 4;
        float4 v = src[ch];
        *(uint2*)&sCT[r][c] = pack4bf(v.x, v.y, v.z, v.w);
      }
    }
    __syncthreads();

    // projections: waves 0,1 -> k (cols 0-47 / 48-95), waves 2,3 -> v
    const unsigned short* Wp = Wb + ((wid < 2) ? OWK : OWV);
    int cf0 = (wid & 1) * 3;
    f32x4 pacc[4][3];
    zacc<4, 3>(pacc);
    domm<4, 3, 3>(&sCT[0][0], 104, Wp, 96, cf0, lane, pacc);
    if (wid < 2) {
#pragma unroll
      for (int b = 0; b < 4; ++b)
#pragma unroll
        for (int cf = 0; cf < 3; ++cf)
#pragma unroll
          for (int r = 0; r < 4; ++r) {
            float v = pacc[b][cf][r];
            pacc[b][cf][r] = v > 0.f ? v : expm1f(v);
          }
    }
    // transposed write: 4 regs = 4 consecutive tokens -> one b64
    {
      unsigned short* dstT = (wid < 2) ? &sEK[0][0] : &sVT[0][0];
#pragma unroll
      for (int b = 0; b < 4; ++b)
#pragma unroll
        for (int cf = 0; cf < 3; ++cf) {
          int col = (cf0 + cf) * 16 + lr;
          int t0 = b * 16 + lg * 4;
          *(uint2*)(dstT + col * 72 + t0) =
              pack4bf(pacc[b][cf][0], pacc[b][cf][1], pacc[b][cf][2], pacc[b][cf][3]);
        }
    }
    __syncthreads();

    // KV accumulation: D[hd][hv] += Ek^T @ V  (block-diag parts used)
    if (wid < 3) {
#pragma unroll
      for (int ks = 0; ks < 2; ++ks) {
        int k0 = ks * 32 + lg * 8;
        short8 a[2];
#pragma unroll
        for (int bb = 0; bb < 2; ++bb)
          a[bb] = *(const short8*)&sEK[(wid * 2 + bb) * 16 + lr][k0];
#pragma unroll
        for (int cf = 0; cf < 6; ++cf) {
          short8 vb = *(const short8*)&sVT[cf * 16 + lr][k0];
#pragma unroll
          for (int bb = 0; bb < 2; ++bb)
            kvacc[bb][cf] = __builtin_amdgcn_mfma_f32_16x16x32_bf16(a[bb], vb, kvacc[bb][cf], 0, 0, 0);
        }
      }
    }
    // column sums of elu(k) and v
    if (tid < 96) {
#pragma unroll
      for (int j = 0; j < 8; ++j) {
        short8 e = *(const short8*)&sEK[tid][j * 8];
        short8 v = *(const short8*)&sVT[tid][j * 8];
#pragma unroll
        for (int q = 0; q < 8; ++q) {
          accEk += b2f((unsigned short)e[q]);
          accV  += b2f((unsigned short)v[q]);
        }
      }
    }
    __syncthreads();
  }

  int slice = blockIdx.x & 15;
  if (tid < 96) {
    atomicAdd((float*)(ws + WS_PSE) + slice * 96 + tid, accEk);
    atomicAdd((float*)(ws + WS_PSV) + slice * 96 + tid, accV);
  }
  if (wid < 3) {
#pragma unroll
    for (int bb = 0; bb < 2; ++bb)
#pragma unroll
      for (int cf = 0; cf < 6; ++cf)
#pragma unroll
        for (int r = 0; r < 4; ++r) {
          int hd = (wid * 2 + bb) * 16 + lg * 4 + r;
          int hv = cf * 16 + lr;
          if (hd / 12 == hv / 12)
            atomicAdd(&pKV[slice * 9216 + hd * 96 + hv], kvacc[bb][cf][r]);
        }
  }
}

// ---------------- finalize: Ksum, KsumTot, BD^T (bf16), CM ------------------
template<int ISBF>
__launch_bounds__(256)
__global__ void kFin(const void* merge_, char* ws) {
  if (((const unsigned*)ws)[0] != (unsigned)ISBF) return;
  __shared__ float Ks[96], sV[96], KV[8][12][12], csk[96];
  int tid = threadIdx.x;
  const float* pSE = (const float*)(ws + WS_PSE);
  const float* pSV = (const float*)(ws + WS_PSV);
  const float* pKV = (const float*)(ws + WS_PKV);
  if (tid < 96) {
    float a = 0.f, b = 0.f;
    for (int s = 0; s < 16; ++s) { a += pSE[s * 96 + tid]; b += pSV[s * 96 + tid]; }
    Ks[tid] = 262144.0f + a;
    sV[tid] = b;
    ((float*)(ws + WS_KSUM))[tid] = Ks[tid];
  }
  __syncthreads();
  if (tid < 8) {
    float s = 0.f;
    for (int d = 0; d < 12; ++d) s += Ks[tid * 12 + d];
    ((float*)(ws + WS_KSTOT))[tid] = s;
  }
  for (int e = tid; e < 1152; e += 256) {
    int h = e / 144, r = e % 144, d = r / 12, v = r % 12;
    int hd = h * 12 + d, hv = h * 12 + v;
    float s = sV[hv];
    for (int sl = 0; sl < 16; ++sl) s += pKV[sl * 9216 + hd * 96 + hv];
    KV[h][d][v] = s * (1.0f / 262144.0f);
  }
  unsigned short* bdt = (unsigned short*)(ws + WS_BDT);
  for (int e = tid; e < 9216; e += 256) bdt[e] = 0;
  __syncthreads();
  for (int e = tid; e < 1152; e += 256) {
    int h = e / 144, r = e % 144, d = r / 12, v = r % 12;
    bdt[(h * 12 + v) * 96 + (h * 12 + d)] = f2b(KV[h][d][v]);
  }
  if (tid < 96) {
    int h = tid / 12, v = tid % 12;
    float s = 0.f;
    for (int d = 0; d < 12; ++d) s += KV[h][d][v];
    csk[tid] = s;
  }
  __syncthreads();
  for (int e = tid; e < 768; e += 256) {
    int h = e / 96, c = e % 96;
    float s = 0.f;
    for (int v = 0; v < 12; ++v) {
      float mg = ISBF ? b2f(((const unsigned short*)merge_)[c * 96 + h * 12 + v])
                      : ((const float*)merge_)[c * 96 + h * 12 + v];
      s += csk[h * 12 + v] * mg;
    }
    ((float*)(ws + WS_CM))[e] = s;
  }
}

// ---------------- kernel B: the per-token chain -----------------------------
template<int ISBF>
__launch_bounds__(128)
__global__ void kB(const void* mr_, void* out_, char* ws) {
  if (((const unsigned*)ws)[0] != (unsigned)ISBF) return;
  __shared__ unsigned short sA[64][200];  // wide ping-pong activation buffer
  __shared__ unsigned short sS[64][104];  // shortcut
  __shared__ unsigned short sY[64][104];  // y
  __shared__ float sZs[64][8];
  const unsigned short* Wb = (const unsigned short*)(ws + WS_WB);
  const float* vec  = (const float*)(ws + WS_VEC);
  const float* Ksum = (const float*)(ws + WS_KSUM);
  const float* KsTot = (const float*)(ws + WS_KSTOT);
  const float* CM = (const float*)(ws + WS_CM);
  const unsigned short* BDT = (const unsigned short*)(ws + WS_BDT);
  int tid = threadIdx.x, lane = tid & 63, wid = tid >> 6;
  int lr = lane & 15, lg = lane >> 4;
  int tok0 = blockIdx.x * 64;

  // S0: stage mr -> sA[:, :96]
  if (ISBF) {
    const uint4v* src = (const uint4v*)((const unsigned short*)mr_ + (size_t)tok0 * 96);
#pragma unroll
    for (int i = 0; i < 6; ++i) {
      int ch = tid * 6 + i;
      int r = ch / 12, c = (ch % 12) * 8;
      *(uint4v*)&sA[r][c] = src[ch];
    }
  } else {
    const float4* src = (const float4*)((const float*)mr_ + (size_t)tok0 * 96);
#pragma unroll
    for (int i = 0; i < 12; ++i) {
      int ch = tid * 12 + i;
      int r = ch / 24, c = (ch % 24) * 4;
      float4 v = src[ch];
      *(uint2*)&sA[r][c] = pack4bf(v.x, v.y, v.z, v.w);
    }
  }
  __syncthreads();

  int row = tid >> 1, c0 = (tid & 1) * 48;

  // LNa: x0 = LN(mr) in place
  {
    float vals[48];
    float s = 0.f, s2 = 0.f;
#pragma unroll
    for (int i = 0; i < 6; ++i) {
      short8 v = *(const short8*)&sA[row][c0 + i * 8];
#pragma unroll
      for (int j = 0; j < 8; ++j) {
        float x = b2f((unsigned short)v[j]);
        vals[i * 8 + j] = x; s += x; s2 += x * x;
      }
    }
    s += __shfl_xor(s, 1); s2 += __shfl_xor(s2, 1);
    float mean = s * (1.f / 96.f);
    float rs = rsqrtf(s2 * (1.f / 96.f) - mean * mean + 1e-5f);
#pragma unroll
    for (int i = 0; i < 6; ++i) {
      short8 o;
#pragma unroll
      for (int j = 0; j < 8; ++j) {
        int c = c0 + i * 8 + j;
        o[j] = (short)f2b((vals[i * 8 + j] - mean) * rs * vec[VLN1W + c] + vec[VLN1B + c]);
      }
      *(short8*)&sA[row][c0 + i * 8] = o;
    }
  }
  __syncthreads();

  f32x4 acc3[4][3];
  f32x4 acc6[4][6];

  // G1: shortcut = x0 @ Wqkv^T -> sS
  zacc<4, 3>(acc3);
  domm<4, 3, 3>(&sA[0][0], 200, Wb + OQKV, 96, wid * 3, lane, acc3);
  writeFrags<4, 3>(&sS[0][0], 104, wid * 3, lane, acc3);
  __syncthreads();

  // G2: y = shortcut @ Wqkv2^T -> sY
  zacc<4, 3>(acc3);
  domm<4, 3, 3>(&sS[0][0], 104, Wb + OQKV2, 96, wid * 3, lane, acc3);
  writeFrags<4, 3>(&sY[0][0], 104, wid * 3, lane, acc3);
  __syncthreads();

  // G3: q = y @ Wq^T ; E = elu(q) -> sA left
  zacc<4, 3>(acc3);
  domm<4, 3, 3>(&sY[0][0], 104, Wb + OWQ, 96, wid * 3, lane, acc3);
#pragma unroll
  for (int b = 0; b < 4; ++b)
#pragma unroll
    for (int cf = 0; cf < 3; ++cf)
#pragma unroll
      for (int r = 0; r < 4; ++r) {
        float v = acc3[b][cf][r];
        acc3[b][cf][r] = v > 0.f ? v : expm1f(v);
      }
  writeFrags<4, 3>(&sA[0][0], 200, wid * 3, lane, acc3);
  __syncthreads();

  // Zs pass: Zs = S / (KsumTot[h] + E.Ksum + eps)
#pragma unroll
  for (int i = 0; i < 4; ++i) {
    int task = tid + 128 * i;
    int zr = task >> 3, h = task & 7;
    float den = KsTot[h];
#pragma unroll
    for (int d = 0; d < 12; ++d)
      den += b2f(sA[zr][h * 12 + d]) * Ksum[h * 12 + d];
    sZs[zr][h] = 262144.0f / (den + 1e-6f);
  }
  __syncthreads();

  // G4: EBD = E @ BD ; T = Zs*EBD -> sA right
  zacc<4, 3>(acc3);
  domm<4, 3, 3>(&sA[0][0], 200, BDT, 96, wid * 3, lane, acc3);
#pragma unroll
  for (int b = 0; b < 4; ++b)
#pragma unroll
    for (int cf = 0; cf < 3; ++cf) {
      int col = (wid * 3 + cf) * 16 + lr;
      int h = col / 12;
#pragma unroll
      for (int r = 0; r < 4; ++r) {
        int rw = b * 16 + lg * 4 + r;
        acc3[b][cf][r] *= sZs[rw][h];
      }
    }
  writeFrags<4, 3>(&sA[0][96], 200, wid * 3, lane, acc3);
  __syncthreads();

  // G5: msgvar = T @ merge^T -> sA left
  zacc<4, 3>(acc3);
  domm<4, 3, 3>(&sA[0][96], 200, Wb + OMERGE, 96, wid * 3, lane, acc3);
  writeFrags<4, 3>(&sA[0][0], 200, wid * 3, lane, acc3);
  __syncthreads();

  // LN1: msg = msgvar + sum_h Zs*CM ; msg~ -> sA right ; copy y -> sA left
  {
    float vals[48];
#pragma unroll
    for (int j = 0; j < 48; ++j) vals[j] = 0.f;
#pragma unroll
    for (int h = 0; h < 8; ++h) {
      float zh = sZs[row][h];
      const float* cmr = CM + h * 96 + c0;
#pragma unroll
      for (int j = 0; j < 48; j += 4) {
        float4 c4 = *(const float4*)(cmr + j);
        vals[j] += zh * c4.x; vals[j + 1] += zh * c4.y;
        vals[j + 2] += zh * c4.z; vals[j + 3] += zh * c4.w;
      }
    }
    float s = 0.f, s2 = 0.f;
#pragma unroll
    for (int i = 0; i < 6; ++i) {
      short8 v = *(const short8*)&sA[row][c0 + i * 8];
#pragma unroll
      for (int j = 0; j < 8; ++j) {
        float x = vals[i * 8 + j] + b2f((unsigned short)v[j]);
        vals[i * 8 + j] = x; s += x; s2 += x * x;
      }
    }
    s += __shfl_xor(s, 1); s2 += __shfl_xor(s2, 1);
    float mean = s * (1.f / 96.f);
    float rs = rsqrtf(s2 * (1.f / 96.f) - mean * mean + 1e-5f);
#pragma unroll
    for (int i = 0; i < 6; ++i) {
      short8 o;
#pragma unroll
      for (int j = 0; j < 8; ++j) {
        int c = c0 + i * 8 + j;
        o[j] = (short)f2b((vals[i * 8 + j] - mean) * rs * vec[VSA1W + c] + vec[VSA1B + c]);
      }
      *(short8*)&sA[row][96 + c0 + i * 8] = o;
    }
#pragma unroll
    for (int i = 0; i < 6; ++i)
      *(uint4v*)&sA[row][c0 + i * 8] = *(const uint4v*)&sY[row][c0 + i * 8];
  }
  __syncthreads();

  // G6: h1 = [y|msg~] @ W1^T ; relu ; -> sA (full width)
  zacc<4, 6>(acc6);
  domm<4, 6, 6>(&sA[0][0], 200, Wb + OW1, 192, wid * 6, lane, acc6);
#pragma unroll
  for (int b = 0; b < 4; ++b)
#pragma unroll
    for (int cf = 0; cf < 6; ++cf)
#pragma unroll
      for (int r = 0; r < 4; ++r)
        acc6[b][cf][r] = fmaxf(acc6[b][cf][r], 0.f);
  __syncthreads();
  writeFrags<4, 6>(&sA[0][0], 200, wid * 6, lane, acc6);
  __syncthreads();

  // G7: h2 = h1r @ W2^T -> sA left
  zacc<4, 3>(acc3);
  domm<4, 3, 6>(&sA[0][0], 200, Wb + OW2, 192, wid * 3, lane, acc3);
  __syncthreads();
  writeFrags<4, 3>(&sA[0][0], 200, wid * 3, lane, acc3);
  __syncthreads();

  // LN(sa_ln2) on h2, x = y + h~, then LN(ln2) over [x | shortcut] -> sA full
  {
    float vals[48];
    float s = 0.f, s2 = 0.f;
#pragma unroll
    for (int i = 0; i < 6; ++i) {
      short8 v = *(const short8*)&sA[row][c0 + i * 8];
#pragma unroll
      for (int j = 0; j < 8; ++j) {
        float x = b2f((unsigned short)v[j]);
        vals[i * 8 + j] = x; s += x; s2 += x * x;
      }
    }
    s += __shfl_xor(s, 1); s2 += __shfl_xor(s2, 1);
    float mh = s * (1.f / 96.f);
    float rh = rsqrtf(s2 * (1.f / 96.f) - mh * mh + 1e-5f);
    float sx = 0.f, sx2 = 0.f;
#pragma unroll
    for (int j = 0; j < 48; ++j) {
      int c = c0 + j;
      float x = b2f(sY[row][c]) + (vals[j] - mh) * rh * vec[VSA2W + c] + vec[VSA2B + c];
      vals[j] = x; sx += x; sx2 += x * x;
    }
#pragma unroll
    for (int j = 0; j < 48; ++j) {
      float sv = b2f(sS[row][c0 + j]);
      sx += sv; sx2 += sv * sv;
    }
    sx += __shfl_xor(sx, 1); sx2 += __shfl_xor(sx2, 1);
    float m2 = sx * (1.f / 192.f);
    float r2 = rsqrtf(sx2 * (1.f / 192.f) - m2 * m2 + 1e-5f);
#pragma unroll
    for (int i = 0; i < 6; ++i) {
      short8 o;
#pragma unroll
      for (int j = 0; j < 8; ++j) {
        int c = c0 + i * 8 + j;
        o[j] = (short)f2b((vals[i * 8 + j] - m2) * r2 * vec[VLN2W + c] + vec[VLN2B + c]);
      }
      *(short8*)&sA[row][c0 + i * 8] = o;
    }
#pragma unroll
    for (int i = 0; i < 6; ++i) {
      short8 o;
#pragma unroll
      for (int j = 0; j < 8; ++j) {
        int c = c0 + i * 8 + j;
        float sv = b2f(sS[row][c]);
        o[j] = (short)f2b((sv - m2) * r2 * vec[VLN2W + 96 + c] + vec[VLN2B + 96 + c]);
      }
      *(short8*)&sA[row][96 + c0 + i * 8] = o;
    }
  }
  __syncthreads();

  // G8: g = gelu(xn @ fc1^T + b1) -> sA full
  zacc<4, 6>(acc6);
  domm<4, 6, 6>(&sA[0][0], 200, Wb + OFC1, 192, wid * 6, lane, acc6);
#pragma unroll
  for (int cf = 0; cf < 6; ++cf) {
    float bb = vec[VFC1B + (wid * 6 + cf) * 16 + lr];
#pragma unroll
    for (int b = 0; b < 4; ++b)
#pragma unroll
      for (int r = 0; r < 4; ++r) {
        float x = acc6[b][cf][r] + bb;
        acc6[b][cf][r] = 0.5f * x * (1.0f + erff(x * 0.70710678118f));
      }
  }
  __syncthreads();
  writeFrags<4, 6>(&sA[0][0], 200, wid * 6, lane, acc6);
  __syncthreads();

  // G9: out = g @ fc2^T + b2 -> global
  zacc<4, 3>(acc3);
  domm<4, 3, 6>(&sA[0][0], 200, Wb + OFC2, 192, wid * 3, lane, acc3);
#pragma unroll
  for (int b = 0; b < 4; ++b)
#pragma unroll
    for (int cf = 0; cf < 3; ++cf)
#pragma unroll
      for (int r = 0; r < 4; ++r) {
        int col = (wid * 3 + cf) * 16 + lr;
        float v = acc3[b][cf][r] + vec[VFC2B + col];
        float v1 = __shfl_xor(v, 1);
        float v2 = __shfl_xor(v, 2);
        float v3 = __shfl_xor(v, 3);
        if ((lane & 3) == 0) {
          size_t token = (size_t)tok0 + b * 16 + lg * 4 + r;
          size_t off = token * 96 + col;
          if (ISBF) {
            *(uint2*)((unsigned short*)out_ + off) = pack4bf(v, v1, v2, v3);
          } else {
            float4 f; f.x = v; f.y = v1; f.z = v2; f.w = v3;
            *(float4*)((float*)out_ + off) = f;
          }
        }
      }
}

// ---------------- launch ----------------------------------------------------
extern "C" void kernel_launch(void* const* d_in, const int* in_sizes, int n_in,
                              void* d_out, int out_size, void* d_ws, size_t ws_size,
                              hipStream_t stream) {
  (void)in_sizes; (void)n_in; (void)out_size; (void)ws_size;
  char* ws = (char*)d_ws;
  probe_k<<<1, 64, 0, stream>>>(d_in[0], (unsigned*)ws);
  InPtrs ip;
  for (int i = 0; i < 23; ++i) ip.p[i] = d_in[i];
  prep_k<0><<<512, 256, 0, stream>>>(ip, ws);
  prep_k<1><<<512, 256, 0, stream>>>(ip, ws);
  kA<0><<<1024, 256, 0, stream>>>(d_in[2], ws);
  kA<1><<<1024, 256, 0, stream>>>(d_in[2], ws);
  kFin<0><<<1, 256, 0, stream>>>(d_in[16], ws);
  kFin<1><<<1, 256, 0, stream>>>(d_in[16], ws);
  kB<0><<<4096, 128, 0, stream>>>(d_in[0], d_out, ws);
  kB<1><<<4096, 128, 0, stream>>>(d_in[0], d_out, ws);
}

// Round 4
// 765.061 us; speedup vs baseline: 1.0169x; 1.0169x over previous
//
#include <hip/hip_runtime.h>
#include <hip/hip_bf16.h>

// ---------------------------------------------------------------------------
// SLENet fused forward on MI355X.
//  kernel A: reduce over warp_ctfeat -> KV[8][12][12], Ksum[96] stats (MFMA)
//  finalize: BD/CM/Ksum derived tables
//  kernel B: per-64-token tile, 9 chained bf16-MFMA GEMMs + LNs, all in LDS
// Q=1+E decomposition keeps the tiny attention signal out of bf16 rounding.
// R4 = exact R1 arithmetic; sY pad trimmed (104->96) so LDS 53248B -> 3
// blocks/CU (was 2). Outputs bit-identical to R1.
// ---------------------------------------------------------------------------

typedef __attribute__((ext_vector_type(8))) short short8;
typedef __attribute__((ext_vector_type(4))) float f32x4;
typedef __attribute__((ext_vector_type(4))) unsigned int uint4v;

#define WS_FLAG 0
#define WS_PKV  512
#define WS_PSV  (WS_PKV + 16*9216*4)
#define WS_PSE  (WS_PSV + 16*96*4)
#define WS_KSUM (WS_PSE + 16*96*4)
#define WS_KSTOT (WS_KSUM + 96*4)
#define WS_CM   (WS_KSTOT + 64)
#define WS_BDT  (WS_CM + 768*4)
#define WS_WB   (WS_BDT + 9216*2)
#define WS_VEC  (WS_WB + 165888*2)

// weight offsets in bf16 elements inside WS_WB
#define OQKV   0
#define OQKV2  9216
#define OWQ    18432
#define OWK    27648
#define OWV    36864
#define OMERGE 46080
#define OW1    55296
#define OW2    92160
#define OFC1   110592
#define OFC2   147456
// vector offsets (f32) inside WS_VEC
#define VLN1W 0
#define VLN1B 96
#define VLN2W 192
#define VLN2B 384
#define VFC1B 576
#define VFC2B 768
#define VSA1W 864
#define VSA1B 960
#define VSA2W 1056
#define VSA2B 1152

struct InPtrs { const void* p[23]; };

__device__ inline float b2f(unsigned short x) {
  union { unsigned u; float f; } c; c.u = ((unsigned)x) << 16; return c.f;
}
__device__ inline unsigned short f2b(float f) {
  __hip_bfloat16 h = __float2bfloat16(f);
  return *(unsigned short*)&h;
}
__device__ inline uint2 pack4bf(float v0, float v1, float v2, float v3) {
  uint2 r;
  r.x = (unsigned)f2b(v0) | ((unsigned)f2b(v1) << 16);
  r.y = (unsigned)f2b(v2) | ((unsigned)f2b(v3) << 16);
  return r;
}

// ---------------- dtype probe: even-index u16s look like bf16 only if bf16 --
__global__ void probe_k(const void* in0, unsigned* flag) {
  int tid = threadIdx.x;
  const unsigned short* u = (const unsigned short*)in0;
  int cnt = 0;
  for (int j = 0; j < 8; ++j) {
    unsigned short v = u[(tid * 8 + j) * 2];
    unsigned e = (v >> 7) & 0xFF;
    if ((e >= 110 && e <= 141) || ((v & 0x7FFF) == 0)) cnt++;
  }
  for (int o = 32; o; o >>= 1) cnt += __shfl_down(cnt, o);
  if (tid == 0) *flag = (cnt > 256) ? 1u : 0u;
}

// ---------------- prep: weights->bf16, vectors->f32, zero reduction buffers -
template<int ISBF>
__launch_bounds__(256)
__global__ void prep_k(InPtrs ip, char* ws) {
  if (((const unsigned*)ws)[0] != (unsigned)ISBF) return;
  const int wsrc[10] = {3,4,13,14,15,16,17,18,9,11};
  const int wdst[11] = {0,9216,18432,27648,36864,46080,55296,92160,110592,147456,165888};
  const int vsrc[10] = {5,6,7,8,10,12,19,20,21,22};
  const int vdst[11] = {0,96,192,384,576,768,864,960,1056,1152,1248};
  unsigned short* wb = (unsigned short*)(ws + WS_WB);
  float* vec = (float*)(ws + WS_VEC);
  float* zr = (float*)(ws + WS_PKV);
  const int TOT = 165888 + 1248 + 150528;
  for (int e = blockIdx.x * 256 + threadIdx.x; e < TOT; e += gridDim.x * 256) {
    if (e < 165888) {
      int w = 0;
      while (w < 9 && e >= wdst[w + 1]) ++w;
      int loc = e - wdst[w];
      if (ISBF) wb[e] = ((const unsigned short*)ip.p[wsrc[w]])[loc];
      else      wb[e] = f2b(((const float*)ip.p[wsrc[w]])[loc]);
    } else if (e < 165888 + 1248) {
      int e2 = e - 165888;
      int w = 0;
      while (w < 9 && e2 >= vdst[w + 1]) ++w;
      int loc = e2 - vdst[w];
      vec[e2] = ISBF ? b2f(((const unsigned short*)ip.p[vsrc[w]])[loc])
                     : ((const float*)ip.p[vsrc[w]])[loc];
    } else {
      zr[e - 165888 - 1248] = 0.0f;
    }
  }
}

// ---------------- generic fragment GEMM helpers ----------------------------
template<int NB, int NCF, int KSTEPS>
__device__ inline void domm(const unsigned short* A, int apitch,
                            const unsigned short* B, int bpitch, int cf0,
                            int lane, f32x4 (&acc)[NB][NCF]) {
  int lr = lane & 15, lg = lane >> 4;
#pragma unroll
  for (int ks = 0; ks < KSTEPS; ++ks) {
    int k0 = ks * 32 + lg * 8;
    short8 bf[NCF];
#pragma unroll
    for (int cf = 0; cf < NCF; ++cf)
      bf[cf] = *(const short8*)(B + ((cf0 + cf) * 16 + lr) * bpitch + k0);
    short8 af[NB];
#pragma unroll
    for (int b = 0; b < NB; ++b)
      af[b] = *(const short8*)(A + (b * 16 + lr) * apitch + k0);
#pragma unroll
    for (int cf = 0; cf < NCF; ++cf)
#pragma unroll
      for (int b = 0; b < NB; ++b)
        acc[b][cf] = __builtin_amdgcn_mfma_f32_16x16x32_bf16(af[b], bf[cf], acc[b][cf], 0, 0, 0);
  }
}

template<int NB, int NCF>
__device__ inline void writeFrags(unsigned short* dst, int pitch, int cf0,
                                  int lane, f32x4 (&acc)[NB][NCF]) {
  int lr = lane & 15, lg = lane >> 4;
#pragma unroll
  for (int b = 0; b < NB; ++b)
#pragma unroll
    for (int cf = 0; cf < NCF; ++cf)
#pragma unroll
      for (int r = 0; r < 4; ++r) {
        float v = acc[b][cf][r];
        float v1 = __shfl_xor(v, 1);
        float v2 = __shfl_xor(v, 2);
        float v3 = __shfl_xor(v, 3);
        if ((lane & 3) == 0) {
          int row = b * 16 + lg * 4 + r;
          int col = (cf0 + cf) * 16 + lr;
          *(uint2*)(dst + row * pitch + col) = pack4bf(v, v1, v2, v3);
        }
      }
}

template<int NB, int NCF>
__device__ inline void zacc(f32x4 (&acc)[NB][NCF]) {
#pragma unroll
  for (int b = 0; b < NB; ++b)
#pragma unroll
    for (int cf = 0; cf < NCF; ++cf)
      acc[b][cf] = (f32x4){0.f, 0.f, 0.f, 0.f};
}

// ---------------- kernel A: stats over warp_ctfeat --------------------------
template<int ISBF>
__launch_bounds__(256)
__global__ void kA(const void* ct_, char* ws) {
  if (((const unsigned*)ws)[0] != (unsigned)ISBF) return;
  __shared__ unsigned short sCT[64][104];
  __shared__ unsigned short sEK[96][72];   // elu(k)^T : [hd][token]
  __shared__ unsigned short sVT[96][72];   // v^T      : [hv][token]
  const unsigned short* Wb = (const unsigned short*)(ws + WS_WB);
  float* pKV = (float*)(ws + WS_PKV);
  int tid = threadIdx.x, lane = tid & 63, wid = tid >> 6;
  int lr = lane & 15, lg = lane >> 4;

  f32x4 kvacc[2][6];
  zacc<2, 6>(kvacc);
  float accEk = 0.f, accV = 0.f;

  for (int t = blockIdx.x; t < 4096; t += gridDim.x) {
    // stage ct tile [64][96] -> sCT bf16
    if (ISBF) {
      const uint4v* src = (const uint4v*)((const unsigned short*)ct_ + (size_t)t * 6144);
#pragma unroll
      for (int i = 0; i < 3; ++i) {
        int ch = tid * 3 + i;
        int r = ch / 12, c = (ch % 12) * 8;
        *(uint4v*)&sCT[r][c] = src[ch];
      }
    } else {
      const float4* src = (const float4*)((const float*)ct_ + (size_t)t * 6144);
#pragma unroll
      for (int i = 0; i < 6; ++i) {
        int ch = tid * 6 + i;
        int r = ch / 24, c = (ch % 24) * 4;
        float4 v = src[ch];
        *(uint2*)&sCT[r][c] = pack4bf(v.x, v.y, v.z, v.w);
      }
    }
    __syncthreads();

    // projections: waves 0,1 -> k (cols 0-47 / 48-95), waves 2,3 -> v
    const unsigned short* Wp = Wb + ((wid < 2) ? OWK : OWV);
    int cf0 = (wid & 1) * 3;
    f32x4 pacc[4][3];
    zacc<4, 3>(pacc);
    domm<4, 3, 3>(&sCT[0][0], 104, Wp, 96, cf0, lane, pacc);
    if (wid < 2) {
#pragma unroll
      for (int b = 0; b < 4; ++b)
#pragma unroll
        for (int cf = 0; cf < 3; ++cf)
#pragma unroll
          for (int r = 0; r < 4; ++r) {
            float v = pacc[b][cf][r];
            pacc[b][cf][r] = v > 0.f ? v : expm1f(v);
          }
    }
    // transposed write: 4 regs = 4 consecutive tokens -> one b64
    {
      unsigned short* dstT = (wid < 2) ? &sEK[0][0] : &sVT[0][0];
#pragma unroll
      for (int b = 0; b < 4; ++b)
#pragma unroll
        for (int cf = 0; cf < 3; ++cf) {
          int col = (cf0 + cf) * 16 + lr;
          int t0 = b * 16 + lg * 4;
          *(uint2*)(dstT + col * 72 + t0) =
              pack4bf(pacc[b][cf][0], pacc[b][cf][1], pacc[b][cf][2], pacc[b][cf][3]);
        }
    }
    __syncthreads();

    // KV accumulation: D[hd][hv] += Ek^T @ V  (block-diag parts used)
    if (wid < 3) {
#pragma unroll
      for (int ks = 0; ks < 2; ++ks) {
        int k0 = ks * 32 + lg * 8;
        short8 a[2];
#pragma unroll
        for (int bb = 0; bb < 2; ++bb)
          a[bb] = *(const short8*)&sEK[(wid * 2 + bb) * 16 + lr][k0];
#pragma unroll
        for (int cf = 0; cf < 6; ++cf) {
          short8 vb = *(const short8*)&sVT[cf * 16 + lr][k0];
#pragma unroll
          for (int bb = 0; bb < 2; ++bb)
            kvacc[bb][cf] = __builtin_amdgcn_mfma_f32_16x16x32_bf16(a[bb], vb, kvacc[bb][cf], 0, 0, 0);
        }
      }
    }
    // column sums of elu(k) and v
    if (tid < 96) {
#pragma unroll
      for (int j = 0; j < 8; ++j) {
        short8 e = *(const short8*)&sEK[tid][j * 8];
        short8 v = *(const short8*)&sVT[tid][j * 8];
#pragma unroll
        for (int q = 0; q < 8; ++q) {
          accEk += b2f((unsigned short)e[q]);
          accV  += b2f((unsigned short)v[q]);
        }
      }
    }
    __syncthreads();
  }

  int slice = blockIdx.x & 15;
  if (tid < 96) {
    atomicAdd((float*)(ws + WS_PSE) + slice * 96 + tid, accEk);
    atomicAdd((float*)(ws + WS_PSV) + slice * 96 + tid, accV);
  }
  if (wid < 3) {
#pragma unroll
    for (int bb = 0; bb < 2; ++bb)
#pragma unroll
      for (int cf = 0; cf < 6; ++cf)
#pragma unroll
        for (int r = 0; r < 4; ++r) {
          int hd = (wid * 2 + bb) * 16 + lg * 4 + r;
          int hv = cf * 16 + lr;
          if (hd / 12 == hv / 12)
            atomicAdd(&pKV[slice * 9216 + hd * 96 + hv], kvacc[bb][cf][r]);
        }
  }
}

// ---------------- finalize: Ksum, KsumTot, BD^T (bf16), CM ------------------
template<int ISBF>
__launch_bounds__(256)
__global__ void kFin(const void* merge_, char* ws) {
  if (((const unsigned*)ws)[0] != (unsigned)ISBF) return;
  __shared__ float Ks[96], sV[96], KV[8][12][12], csk[96];
  int tid = threadIdx.x;
  const float* pSE = (const float*)(ws + WS_PSE);
  const float* pSV = (const float*)(ws + WS_PSV);
  const float* pKV = (const float*)(ws + WS_PKV);
  if (tid < 96) {
    float a = 0.f, b = 0.f;
    for (int s = 0; s < 16; ++s) { a += pSE[s * 96 + tid]; b += pSV[s * 96 + tid]; }
    Ks[tid] = 262144.0f + a;
    sV[tid] = b;
    ((float*)(ws + WS_KSUM))[tid] = Ks[tid];
  }
  __syncthreads();
  if (tid < 8) {
    float s = 0.f;
    for (int d = 0; d < 12; ++d) s += Ks[tid * 12 + d];
    ((float*)(ws + WS_KSTOT))[tid] = s;
  }
  for (int e = tid; e < 1152; e += 256) {
    int h = e / 144, r = e % 144, d = r / 12, v = r % 12;
    int hd = h * 12 + d, hv = h * 12 + v;
    float s = sV[hv];
    for (int sl = 0; sl < 16; ++sl) s += pKV[sl * 9216 + hd * 96 + hv];
    KV[h][d][v] = s * (1.0f / 262144.0f);
  }
  unsigned short* bdt = (unsigned short*)(ws + WS_BDT);
  for (int e = tid; e < 9216; e += 256) bdt[e] = 0;
  __syncthreads();
  for (int e = tid; e < 1152; e += 256) {
    int h = e / 144, r = e % 144, d = r / 12, v = r % 12;
    bdt[(h * 12 + v) * 96 + (h * 12 + d)] = f2b(KV[h][d][v]);
  }
  if (tid < 96) {
    int h = tid / 12, v = tid % 12;
    float s = 0.f;
    for (int d = 0; d < 12; ++d) s += KV[h][d][v];
    csk[tid] = s;
  }
  __syncthreads();
  for (int e = tid; e < 768; e += 256) {
    int h = e / 96, c = e % 96;
    float s = 0.f;
    for (int v = 0; v < 12; ++v) {
      float mg = ISBF ? b2f(((const unsigned short*)merge_)[c * 96 + h * 12 + v])
                      : ((const float*)merge_)[c * 96 + h * 12 + v];
      s += csk[h * 12 + v] * mg;
    }
    ((float*)(ws + WS_CM))[e] = s;
  }
}

// ---------------- kernel B: the per-token chain -----------------------------
template<int ISBF>
__launch_bounds__(128)
__global__ void kB(const void* mr_, void* out_, char* ws) {
  if (((const unsigned*)ws)[0] != (unsigned)ISBF) return;
  __shared__ unsigned short sA[64][200];  // wide ping-pong activation buffer
  __shared__ unsigned short sS[64][104];  // shortcut
  __shared__ unsigned short sY[64][96];   // y (pad trimmed: 3 blocks/CU)
  __shared__ float sZs[64][8];
  const unsigned short* Wb = (const unsigned short*)(ws + WS_WB);
  const float* vec  = (const float*)(ws + WS_VEC);
  const float* Ksum = (const float*)(ws + WS_KSUM);
  const float* KsTot = (const float*)(ws + WS_KSTOT);
  const float* CM = (const float*)(ws + WS_CM);
  const unsigned short* BDT = (const unsigned short*)(ws + WS_BDT);
  int tid = threadIdx.x, lane = tid & 63, wid = tid >> 6;
  int lr = lane & 15, lg = lane >> 4;
  int tok0 = blockIdx.x * 64;

  // S0: stage mr -> sA[:, :96]
  if (ISBF) {
    const uint4v* src = (const uint4v*)((const unsigned short*)mr_ + (size_t)tok0 * 96);
#pragma unroll
    for (int i = 0; i < 6; ++i) {
      int ch = tid * 6 + i;
      int r = ch / 12, c = (ch % 12) * 8;
      *(uint4v*)&sA[r][c] = src[ch];
    }
  } else {
    const float4* src = (const float4*)((const float*)mr_ + (size_t)tok0 * 96);
#pragma unroll
    for (int i = 0; i < 12; ++i) {
      int ch = tid * 12 + i;
      int r = ch / 24, c = (ch % 24) * 4;
      float4 v = src[ch];
      *(uint2*)&sA[r][c] = pack4bf(v.x, v.y, v.z, v.w);
    }
  }
  __syncthreads();

  int row = tid >> 1, c0 = (tid & 1) * 48;

  // LNa: x0 = LN(mr) in place
  {
    float vals[48];
    float s = 0.f, s2 = 0.f;
#pragma unroll
    for (int i = 0; i < 6; ++i) {
      short8 v = *(const short8*)&sA[row][c0 + i * 8];
#pragma unroll
      for (int j = 0; j < 8; ++j) {
        float x = b2f((unsigned short)v[j]);
        vals[i * 8 + j] = x; s += x; s2 += x * x;
      }
    }
    s += __shfl_xor(s, 1); s2 += __shfl_xor(s2, 1);
    float mean = s * (1.f / 96.f);
    float rs = rsqrtf(s2 * (1.f / 96.f) - mean * mean + 1e-5f);
#pragma unroll
    for (int i = 0; i < 6; ++i) {
      short8 o;
#pragma unroll
      for (int j = 0; j < 8; ++j) {
        int c = c0 + i * 8 + j;
        o[j] = (short)f2b((vals[i * 8 + j] - mean) * rs * vec[VLN1W + c] + vec[VLN1B + c]);
      }
      *(short8*)&sA[row][c0 + i * 8] = o;
    }
  }
  __syncthreads();

  f32x4 acc3[4][3];
  f32x4 acc6[4][6];

  // G1: shortcut = x0 @ Wqkv^T -> sS
  zacc<4, 3>(acc3);
  domm<4, 3, 3>(&sA[0][0], 200, Wb + OQKV, 96, wid * 3, lane, acc3);
  writeFrags<4, 3>(&sS[0][0], 104, wid * 3, lane, acc3);
  __syncthreads();

  // G2: y = shortcut @ Wqkv2^T -> sY
  zacc<4, 3>(acc3);
  domm<4, 3, 3>(&sS[0][0], 104, Wb + OQKV2, 96, wid * 3, lane, acc3);
  writeFrags<4, 3>(&sY[0][0], 96, wid * 3, lane, acc3);
  __syncthreads();

  // G3: q = y @ Wq^T ; E = elu(q) -> sA left
  zacc<4, 3>(acc3);
  domm<4, 3, 3>(&sY[0][0], 96, Wb + OWQ, 96, wid * 3, lane, acc3);
#pragma unroll
  for (int b = 0; b < 4; ++b)
#pragma unroll
    for (int cf = 0; cf < 3; ++cf)
#pragma unroll
      for (int r = 0; r < 4; ++r) {
        float v = acc3[b][cf][r];
        acc3[b][cf][r] = v > 0.f ? v : expm1f(v);
      }
  writeFrags<4, 3>(&sA[0][0], 200, wid * 3, lane, acc3);
  __syncthreads();

  // Zs pass: Zs = S / (KsumTot[h] + E.Ksum + eps)
#pragma unroll
  for (int i = 0; i < 4; ++i) {
    int task = tid + 128 * i;
    int zr = task >> 3, h = task & 7;
    float den = KsTot[h];
#pragma unroll
    for (int d = 0; d < 12; ++d)
      den += b2f(sA[zr][h * 12 + d]) * Ksum[h * 12 + d];
    sZs[zr][h] = 262144.0f / (den + 1e-6f);
  }
  __syncthreads();

  // G4: EBD = E @ BD ; T = Zs*EBD -> sA right
  zacc<4, 3>(acc3);
  domm<4, 3, 3>(&sA[0][0], 200, BDT, 96, wid * 3, lane, acc3);
#pragma unroll
  for (int b = 0; b < 4; ++b)
#pragma unroll
    for (int cf = 0; cf < 3; ++cf) {
      int col = (wid * 3 + cf) * 16 + lr;
      int h = col / 12;
#pragma unroll
      for (int r = 0; r < 4; ++r) {
        int rw = b * 16 + lg * 4 + r;
        acc3[b][cf][r] *= sZs[rw][h];
      }
    }
  writeFrags<4, 3>(&sA[0][96], 200, wid * 3, lane, acc3);
  __syncthreads();

  // G5: msgvar = T @ merge^T -> sA left
  zacc<4, 3>(acc3);
  domm<4, 3, 3>(&sA[0][96], 200, Wb + OMERGE, 96, wid * 3, lane, acc3);
  writeFrags<4, 3>(&sA[0][0], 200, wid * 3, lane, acc3);
  __syncthreads();

  // LN1: msg = msgvar + sum_h Zs*CM ; msg~ -> sA right ; copy y -> sA left
  {
    float vals[48];
#pragma unroll
    for (int j = 0; j < 48; ++j) vals[j] = 0.f;
#pragma unroll
    for (int h = 0; h < 8; ++h) {
      float zh = sZs[row][h];
      const float* cmr = CM + h * 96 + c0;
#pragma unroll
      for (int j = 0; j < 48; j += 4) {
        float4 c4 = *(const float4*)(cmr + j);
        vals[j] += zh * c4.x; vals[j + 1] += zh * c4.y;
        vals[j + 2] += zh * c4.z; vals[j + 3] += zh * c4.w;
      }
    }
    float s = 0.f, s2 = 0.f;
#pragma unroll
    for (int i = 0; i < 6; ++i) {
      short8 v = *(const short8*)&sA[row][c0 + i * 8];
#pragma unroll
      for (int j = 0; j < 8; ++j) {
        float x = vals[i * 8 + j] + b2f((unsigned short)v[j]);
        vals[i * 8 + j] = x; s += x; s2 += x * x;
      }
    }
    s += __shfl_xor(s, 1); s2 += __shfl_xor(s2, 1);
    float mean = s * (1.f / 96.f);
    float rs = rsqrtf(s2 * (1.f / 96.f) - mean * mean + 1e-5f);
#pragma unroll
    for (int i = 0; i < 6; ++i) {
      short8 o;
#pragma unroll
      for (int j = 0; j < 8; ++j) {
        int c = c0 + i * 8 + j;
        o[j] = (short)f2b((vals[i * 8 + j] - mean) * rs * vec[VSA1W + c] + vec[VSA1B + c]);
      }
      *(short8*)&sA[row][96 + c0 + i * 8] = o;
    }
#pragma unroll
    for (int i = 0; i < 6; ++i)
      *(uint4v*)&sA[row][c0 + i * 8] = *(const uint4v*)&sY[row][c0 + i * 8];
  }
  __syncthreads();

  // G6: h1 = [y|msg~] @ W1^T ; relu ; -> sA (full width)
  zacc<4, 6>(acc6);
  domm<4, 6, 6>(&sA[0][0], 200, Wb + OW1, 192, wid * 6, lane, acc6);
#pragma unroll
  for (int b = 0; b < 4; ++b)
#pragma unroll
    for (int cf = 0; cf < 6; ++cf)
#pragma unroll
      for (int r = 0; r < 4; ++r)
        acc6[b][cf][r] = fmaxf(acc6[b][cf][r], 0.f);
  __syncthreads();
  writeFrags<4, 6>(&sA[0][0], 200, wid * 6, lane, acc6);
  __syncthreads();

  // G7: h2 = h1r @ W2^T -> sA left
  zacc<4, 3>(acc3);
  domm<4, 3, 6>(&sA[0][0], 200, Wb + OW2, 192, wid * 3, lane, acc3);
  __syncthreads();
  writeFrags<4, 3>(&sA[0][0], 200, wid * 3, lane, acc3);
  __syncthreads();

  // LN(sa_ln2) on h2, x = y + h~, then LN(ln2) over [x | shortcut] -> sA full
  {
    float vals[48];
    float s = 0.f, s2 = 0.f;
#pragma unroll
    for (int i = 0; i < 6; ++i) {
      short8 v = *(const short8*)&sA[row][c0 + i * 8];
#pragma unroll
      for (int j = 0; j < 8; ++j) {
        float x = b2f((unsigned short)v[j]);
        vals[i * 8 + j] = x; s += x; s2 += x * x;
      }
    }
    s += __shfl_xor(s, 1); s2 += __shfl_xor(s2, 1);
    float mh = s * (1.f / 96.f);
    float rh = rsqrtf(s2 * (1.f / 96.f) - mh * mh + 1e-5f);
    float sx = 0.f, sx2 = 0.f;
#pragma unroll
    for (int j = 0; j < 48; ++j) {
      int c = c0 + j;
      float x = b2f(sY[row][c]) + (vals[j] - mh) * rh * vec[VSA2W + c] + vec[VSA2B + c];
      vals[j] = x; sx += x; sx2 += x * x;
    }
#pragma unroll
    for (int j = 0; j < 48; ++j) {
      float sv = b2f(sS[row][c0 + j]);
      sx += sv; sx2 += sv * sv;
    }
    sx += __shfl_xor(sx, 1); sx2 += __shfl_xor(sx2, 1);
    float m2 = sx * (1.f / 192.f);
    float r2 = rsqrtf(sx2 * (1.f / 192.f) - m2 * m2 + 1e-5f);
#pragma unroll
    for (int i = 0; i < 6; ++i) {
      short8 o;
#pragma unroll
      for (int j = 0; j < 8; ++j) {
        int c = c0 + i * 8 + j;
        o[j] = (short)f2b((vals[i * 8 + j] - m2) * r2 * vec[VLN2W + c] + vec[VLN2B + c]);
      }
      *(short8*)&sA[row][c0 + i * 8] = o;
    }
#pragma unroll
    for (int i = 0; i < 6; ++i) {
      short8 o;
#pragma unroll
      for (int j = 0; j < 8; ++j) {
        int c = c0 + i * 8 + j;
        float sv = b2f(sS[row][c]);
        o[j] = (short)f2b((sv - m2) * r2 * vec[VLN2W + 96 + c] + vec[VLN2B + 96 + c]);
      }
      *(short8*)&sA[row][96 + c0 + i * 8] = o;
    }
  }
  __syncthreads();

  // G8: g = gelu(xn @ fc1^T + b1) -> sA full
  zacc<4, 6>(acc6);
  domm<4, 6, 6>(&sA[0][0], 200, Wb + OFC1, 192, wid * 6, lane, acc6);
#pragma unroll
  for (int cf = 0; cf < 6; ++cf) {
    float bb = vec[VFC1B + (wid * 6 + cf) * 16 + lr];
#pragma unroll
    for (int b = 0; b < 4; ++b)
#pragma unroll
      for (int r = 0; r < 4; ++r) {
        float x = acc6[b][cf][r] + bb;
        acc6[b][cf][r] = 0.5f * x * (1.0f + erff(x * 0.70710678118f));
      }
  }
  __syncthreads();
  writeFrags<4, 6>(&sA[0][0], 200, wid * 6, lane, acc6);
  __syncthreads();

  // G9: out = g @ fc2^T + b2 -> global
  zacc<4, 3>(acc3);
  domm<4, 3, 6>(&sA[0][0], 200, Wb + OFC2, 192, wid * 3, lane, acc3);
#pragma unroll
  for (int b = 0; b < 4; ++b)
#pragma unroll
    for (int cf = 0; cf < 3; ++cf)
#pragma unroll
      for (int r = 0; r < 4; ++r) {
        int col = (wid * 3 + cf) * 16 + lr;
        float v = acc3[b][cf][r] + vec[VFC2B + col];
        float v1 = __shfl_xor(v, 1);
        float v2 = __shfl_xor(v, 2);
        float v3 = __shfl_xor(v, 3);
        if ((lane & 3) == 0) {
          size_t token = (size_t)tok0 + b * 16 + lg * 4 + r;
          size_t off = token * 96 + col;
          if (ISBF) {
            *(uint2*)((unsigned short*)out_ + off) = pack4bf(v, v1, v2, v3);
          } else {
            float4 f; f.x = v; f.y = v1; f.z = v2; f.w = v3;
            *(float4*)((float*)out_ + off) = f;
          }
        }
      }
}

// ---------------- launch ----------------------------------------------------
extern "C" void kernel_launch(void* const* d_in, const int* in_sizes, int n_in,
                              void* d_out, int out_size, void* d_ws, size_t ws_size,
                              hipStream_t stream) {
  (void)in_sizes; (void)n_in; (void)out_size; (void)ws_size;
  char* ws = (char*)d_ws;
  probe_k<<<1, 64, 0, stream>>>(d_in[0], (unsigned*)ws);
  InPtrs ip;
  for (int i = 0; i < 23; ++i) ip.p[i] = d_in[i];
  prep_k<0><<<512, 256, 0, stream>>>(ip, ws);
  prep_k<1><<<512, 256, 0, stream>>>(ip, ws);
  kA<0><<<1024, 256, 0, stream>>>(d_in[2], ws);
  kA<1><<<1024, 256, 0, stream>>>(d_in[2], ws);
  kFin<0><<<1, 256, 0, stream>>>(d_in[16], ws);
  kFin<1><<<1, 256, 0, stream>>>(d_in[16], ws);
  kB<0><<<4096, 128, 0, stream>>>(d_in[0], d_out, ws);
  kB<1><<<4096, 128, 0, stream>>>(d_in[0], d_out, ws);
}